// Round 6
// baseline (828.537 us; speedup 1.0000x reference)
//
#include <hip/hip_runtime.h>
#include <cstdint>
#include <cstddef>

#define DIMN 2048
#define SEQ  2048
#define NB   2
#define NH   16
#define DH   128

typedef __bf16 bf16x8 __attribute__((ext_vector_type(8)));
typedef float  f32x4  __attribute__((ext_vector_type(4)));
typedef bf16x8 __attribute__((may_alias)) bf16x8_a;
typedef ushort4 __attribute__((may_alias)) ushort4_a;
typedef float4 __attribute__((may_alias)) float4_a;

// ---- bf16 <-> f32 helpers on raw ushort storage (RNE, matches np/jnp) ----
__device__ __forceinline__ float b2f(unsigned short b) {
    unsigned u = ((unsigned)b) << 16; float f; __builtin_memcpy(&f, &u, 4); return f;
}
__device__ __forceinline__ unsigned short f2b(float f) {
    unsigned u; __builtin_memcpy(&u, &f, 4);
    u = (u + 0x7FFFu + ((u >> 16) & 1u)) >> 16;
    return (unsigned short)u;
}
__device__ __forceinline__ __bf16 f2bf(float f) {
    unsigned short us = f2b(f); __bf16 h; __builtin_memcpy(&h, &us, 2); return h;
}

// dtype flag: freqs_cos[0]==1.0 -> fp32 word0 = 0x3F800000 (bf16 would be 0x3F803F80)
__device__ __forceinline__ bool dt_is_f32(const void* fc) {
    return ((const unsigned int*)fc)[0] == 0x3F800000u;
}

// async global->LDS, 16B per lane (LDS dest = wave-uniform base + lane*16)
__device__ __forceinline__ void gload_lds16(const unsigned short* g, unsigned short* l) {
    __builtin_amdgcn_global_load_lds(
        (const __attribute__((address_space(1))) void*)g,
        (__attribute__((address_space(3))) void*)l,
        16, 0, 0);
}

// ============== convert fp32 (or bf16 passthrough) -> bf16, 8 elems/thread ==============
__global__ void convert_kernel(const void* __restrict__ in, unsigned short* __restrict__ out,
                               int n8, const void* __restrict__ dt)
{
    const bool isf32 = dt_is_f32(dt);
    int i = blockIdx.x * 256 + threadIdx.x;
    if (i >= n8) return;
    if (isf32) {
        const float* p = (const float*)in + (size_t)i * 8;
        float4 lo = *(const float4_a*)p;
        float4 hi = *(const float4_a*)(p + 4);
        ushort4 a, b;
        a.x = f2b(lo.x); a.y = f2b(lo.y); a.z = f2b(lo.z); a.w = f2b(lo.w);
        b.x = f2b(hi.x); b.y = f2b(hi.y); b.z = f2b(hi.z); b.w = f2b(hi.w);
        *(ushort4_a*)(out + (size_t)i * 8)     = a;
        *(ushort4_a*)(out + (size_t)i * 8 + 4) = b;
    } else {
        const ushort4* p = (const ushort4*)((const char*)in + (size_t)i * 16);
        *(ushort4_a*)(out + (size_t)i * 8)     = p[0];
        *(ushort4_a*)(out + (size_t)i * 8 + 4) = p[1];
    }
}

// =====================================================================
// "bt" GEMM, pure bf16 inputs:  C[m,n] = scale * sum_k A[m,k]*B[n,k]  (fp32 acc)
// A row-major [M,K] lda; B row-major [N,K] ldb; C row-major ldc.
// cmode: 1 = C dtype follows runtime flag (fp32 if flag), 0 = bf16 always.
// grid.z -> (zb,zh) = (z/Hz, z%Hz).  (m97 structure, global_load_lds width-16)
// =====================================================================
__global__ __launch_bounds__(256, 2) void gemm_bt(
    const unsigned short* __restrict__ A, const unsigned short* __restrict__ B,
    void* __restrict__ C, const void* __restrict__ dt, int cmode,
    int K, int lda, int ldb, int ldc, int Hz,
    long long sAb, long long sAh, long long sBb, long long sBh,
    long long sCb, long long sCh, float scale)
{
    const bool cf32 = cmode && dt_is_f32(dt);

    int bx = blockIdx.x, by = blockIdx.y, z = blockIdx.z;
    int zb = z / Hz, zh = z - zb * Hz;
    const unsigned short* Az = A + zb * sAb + zh * sAh;
    const unsigned short* Bz = B + zb * sBb + zh * sBh;
    const long long coffz = zb * sCb + zh * sCh;
    const int m0 = by * 128, n0 = bx * 128;

    __shared__ alignas(16) unsigned short sA[128 * 32];
    __shared__ alignas(16) unsigned short sB[128 * 32];

    const int tid  = threadIdx.x;
    const int lane = tid & 63, wave = tid >> 6;
    const int waveM = wave >> 1, waveN = wave & 1;

    const int rowA = tid >> 2;          // 0..63
    const int c8   = (tid & 3) << 3;    // 0,8,16,24
    const unsigned short* gA0 = Az + (size_t)(m0 + rowA)      * lda + c8;
    const unsigned short* gA1 = Az + (size_t)(m0 + rowA + 64) * lda + c8;
    const unsigned short* gB0 = Bz + (size_t)(n0 + rowA)      * ldb + c8;
    const unsigned short* gB1 = Bz + (size_t)(n0 + rowA + 64) * ldb + c8;
    unsigned short* lA0 = sA + tid * 8;
    unsigned short* lA1 = sA + 2048 + tid * 8;
    unsigned short* lB0 = sB + tid * 8;
    unsigned short* lB1 = sB + 2048 + tid * 8;

    f32x4 acc[4][4];
    #pragma unroll
    for (int i = 0; i < 4; i++)
        #pragma unroll
        for (int j = 0; j < 4; j++)
            acc[i][j] = (f32x4){0.f, 0.f, 0.f, 0.f};

    const int fr = lane & 15, fq = lane >> 4;
    const int aoff = (waveM * 64 + fr) * 32 + fq * 8;
    const int boff = (waveN * 64 + fr) * 32 + fq * 8;

    for (int kt = 0; kt < K; kt += 32) {
        gload_lds16(gA0, lA0);
        gload_lds16(gA1, lA1);
        gload_lds16(gB0, lB0);
        gload_lds16(gB1, lB1);
        gA0 += 32; gA1 += 32; gB0 += 32; gB1 += 32;
        __syncthreads();

        bf16x8 af[4], bfr[4];
        #pragma unroll
        for (int mt = 0; mt < 4; mt++)
            af[mt] = *(const bf16x8_a*)(sA + aoff + mt * 16 * 32);
        #pragma unroll
        for (int nt = 0; nt < 4; nt++)
            bfr[nt] = *(const bf16x8_a*)(sB + boff + nt * 16 * 32);
        #pragma unroll
        for (int mt = 0; mt < 4; mt++)
            #pragma unroll
            for (int nt = 0; nt < 4; nt++)
                acc[mt][nt] = __builtin_amdgcn_mfma_f32_16x16x32_bf16(
                    af[mt], bfr[nt], acc[mt][nt], 0, 0, 0);
        __syncthreads();
    }

    // C/D layout: col = lane&15 (n), row = (lane>>4)*4 + r (m)
    const int crow0 = m0 + waveM * 64 + fq * 4;
    const int ccol0 = n0 + waveN * 64 + fr;
    #pragma unroll
    for (int mt = 0; mt < 4; mt++)
        #pragma unroll
        for (int nt = 0; nt < 4; nt++) {
            size_t base = (size_t)(crow0 + mt * 16) * ldc + (ccol0 + nt * 16);
            if (cf32) {
                float* Cz = (float*)C + coffz;
                #pragma unroll
                for (int r = 0; r < 4; r++)
                    Cz[base + (size_t)r * ldc] = acc[mt][nt][r] * scale;
            } else {
                unsigned short* Cz = (unsigned short*)C + coffz;
                #pragma unroll
                for (int r = 0; r < 4; r++)
                    Cz[base + (size_t)r * ldc] = f2b(acc[mt][nt][r] * scale);
            }
        }
}

// ============== RoPE in place on q_lin and k_lin [NB*SEQ, DIMN] bf16, 8 elems/thread ==============
__global__ void rope_kernel(unsigned short* q, unsigned short* k,
                            const void* __restrict__ fc,
                            const void* __restrict__ fs)
{
    const bool isf32 = dt_is_f32(fc);
    int idx = blockIdx.x * 256 + threadIdx.x;   // 8-elem group
    unsigned short* p = blockIdx.y ? k : q;
    int row = idx >> 8;                         // [0, NB*SEQ)
    int e   = (idx & 255) << 3;                 // feature 0..2047 step 8
    int s   = row & (SEQ - 1);
    int j0  = (e & (DH - 1)) >> 1;              // 4 pairs j0..j0+3
    float c[4], sn[4];
    #pragma unroll
    for (int t = 0; t < 4; t++) {
        if (isf32) {
            c[t]  = ((const float*)fc)[s * 64 + j0 + t];
            sn[t] = ((const float*)fs)[s * 64 + j0 + t];
        } else {
            c[t]  = b2f(((const unsigned short*)fc)[s * 64 + j0 + t]);
            sn[t] = b2f(((const unsigned short*)fs)[s * 64 + j0 + t]);
        }
    }
    size_t off = (size_t)row * DIMN + e;
    ushort4 a = *(ushort4_a*)(p + off);
    ushort4 b = *(ushort4_a*)(p + off + 4);
    float xs[8] = {b2f(a.x), b2f(a.y), b2f(a.z), b2f(a.w),
                   b2f(b.x), b2f(b.y), b2f(b.z), b2f(b.w)};
    ushort4 oa, ob;
    oa.x = f2b(xs[0] * c[0] - xs[1] * sn[0]);
    oa.y = f2b(xs[0] * sn[0] + xs[1] * c[0]);
    oa.z = f2b(xs[2] * c[1] - xs[3] * sn[1]);
    oa.w = f2b(xs[2] * sn[1] + xs[3] * c[1]);
    ob.x = f2b(xs[4] * c[2] - xs[5] * sn[2]);
    ob.y = f2b(xs[4] * sn[2] + xs[5] * c[2]);
    ob.z = f2b(xs[6] * c[3] - xs[7] * sn[3]);
    ob.w = f2b(xs[6] * sn[3] + xs[7] * c[3]);
    *(ushort4_a*)(p + off)     = oa;
    *(ushort4_a*)(p + off + 4) = ob;
}

// ============== per-batch 2048x2048 transpose: out[i][t] = in[t][i] (bf16) ==============
__global__ void transpose_kernel(const unsigned short* __restrict__ in,
                                 unsigned short* __restrict__ out)
{
    __shared__ unsigned short tile[32][33];
    int b = blockIdx.z;
    const unsigned short* ib = in + (size_t)b * SEQ * DIMN;
    unsigned short*       ob = out + (size_t)b * SEQ * DIMN;
    int t0 = blockIdx.x << 5, i0 = blockIdx.y << 5;
    int c = threadIdx.x & 31, r0 = threadIdx.x >> 5;
    for (int r = r0; r < 32; r += 8)
        tile[r][c] = ib[(size_t)(t0 + r) * DIMN + i0 + c];
    __syncthreads();
    for (int r = r0; r < 32; r += 8)
        ob[(size_t)(i0 + r) * SEQ + t0 + c] = tile[c][r];
}

// =====================================================================
// Fused flash attention (causal) — R5-verified structure; LDS trimmed to
// 51 KB (3 blocks/CU): sP de-padded (stride 64) with XOR chunk swizzle.
// Block: (q-tile of 128 rows, b, h); wave w owns q rows [w*32, w*32+32).
// KV tiles of 64. Writes ctxT[dh][s] (transposed) directly.
// =====================================================================
#define KPAD 136   // 128 + 8 (16B-mult stride)
#define VPAD 72    // 64 + 8
__global__ __launch_bounds__(256, 3) void flash_kernel(
    const unsigned short* __restrict__ q_lin,
    const unsigned short* __restrict__ k_lin,
    const unsigned short* __restrict__ vTg,
    unsigned short* __restrict__ ctxT)
{
    __shared__ alignas(16) __bf16 sK[64 * KPAD];    // K tile [t][dh]     17408 B
    __shared__ alignas(16) __bf16 sV[DH * VPAD];    // V^T tile [dh][t]   18432 B
    __shared__ alignas(16) __bf16 sP[128 * 64];     // P [q][t] XOR-swz   16384 B

    const int qt = blockIdx.x;
    const int z  = blockIdx.y;
    const int b  = z >> 4, h = z & 15;

    const unsigned short* Qg = q_lin + ((size_t)(b * SEQ + qt * 128)) * DIMN + h * DH;
    const unsigned short* Kg = k_lin + (size_t)b * SEQ * DIMN + h * DH;
    const unsigned short* Vg = vTg  + (size_t)b * SEQ * DIMN + (size_t)h * DH * SEQ;
    unsigned short*       Cg = ctxT + (size_t)b * SEQ * DIMN + (size_t)h * DH * SEQ;

    const int tid  = threadIdx.x;
    const int lane = tid & 63, wave = tid >> 6;
    const int fr = lane & 15, fq = lane >> 4;

    // Q fragments (A-layout): row = wave*32 + mt*16 + fr, k = kt*32 + fq*8 + j
    bf16x8 qf[2][4];
    #pragma unroll
    for (int mt = 0; mt < 2; mt++)
        #pragma unroll
        for (int kt = 0; kt < 4; kt++)
            qf[mt][kt] = *(const bf16x8_a*)(Qg + (size_t)(wave * 32 + mt * 16 + fr) * DIMN + kt * 32 + fq * 8);

    f32x4 o_acc[2][8];
    #pragma unroll
    for (int mt = 0; mt < 2; mt++)
        #pragma unroll
        for (int nt = 0; nt < 8; nt++)
            o_acc[mt][nt] = (f32x4){0.f, 0.f, 0.f, 0.f};
    float m_st[2][4], l_st[2][4];
    #pragma unroll
    for (int mt = 0; mt < 2; mt++)
        #pragma unroll
        for (int r = 0; r < 4; r++) { m_st[mt][r] = -1e30f; l_st[mt][r] = 0.f; }

    const float scale = 0.08838834764831845f;
    const int jmax = 2 * qt + 2;

    for (int jt = 0; jt < jmax; jt++) {
        __syncthreads();
        const unsigned short* Kt = Kg + (size_t)jt * 64 * DIMN;
        const unsigned short* Vt = Vg + jt * 64;
        #pragma unroll
        for (int i = 0; i < 4; i++) {
            int cc  = tid + i * 256;
            int row = cc >> 4, col = (cc & 15) << 3;
            *(bf16x8_a*)(sK + row * KPAD + col) = *(const bf16x8_a*)(Kt + (size_t)row * DIMN + col);
        }
        #pragma unroll
        for (int i = 0; i < 4; i++) {
            int cc  = tid + i * 256;
            int row = cc >> 3, col = (cc & 7) << 3;
            *(bf16x8_a*)(sV + row * VPAD + col) = *(const bf16x8_a*)(Vt + (size_t)row * SEQ + col);
        }
        __syncthreads();

        // S = Q . K^T
        f32x4 s_acc[2][4];
        #pragma unroll
        for (int mt = 0; mt < 2; mt++)
            #pragma unroll
            for (int nt = 0; nt < 4; nt++)
                s_acc[mt][nt] = (f32x4){0.f, 0.f, 0.f, 0.f};
        #pragma unroll
        for (int kt = 0; kt < 4; kt++) {
            bf16x8 kf[4];
            #pragma unroll
            for (int nt = 0; nt < 4; nt++)
                kf[nt] = *(const bf16x8_a*)(sK + (nt * 16 + fr) * KPAD + kt * 32 + fq * 8);
            #pragma unroll
            for (int mt = 0; mt < 2; mt++)
                #pragma unroll
                for (int nt = 0; nt < 4; nt++)
                    s_acc[mt][nt] = __builtin_amdgcn_mfma_f32_16x16x32_bf16(
                        qf[mt][kt], kf[nt], s_acc[mt][nt], 0, 0, 0);
        }

        #pragma unroll
        for (int mt = 0; mt < 2; mt++)
            #pragma unroll
            for (int nt = 0; nt < 4; nt++)
                #pragma unroll
                for (int r = 0; r < 4; r++)
                    s_acc[mt][nt][r] *= scale;
        if (jt >= 2 * qt) {
            #pragma unroll
            for (int mt = 0; mt < 2; mt++)
                #pragma unroll
                for (int nt = 0; nt < 4; nt++)
                    #pragma unroll
                    for (int r = 0; r < 4; r++) {
                        int srow = wave * 32 + mt * 16 + fq * 4 + r;
                        int tcol = jt * 64 + nt * 16 + fr - qt * 128;
                        if (tcol > srow) s_acc[mt][nt][r] = -1e30f;
                    }
        }

        // online softmax
        float al[2][4];
        #pragma unroll
        for (int mt = 0; mt < 2; mt++)
            #pragma unroll
            for (int r = 0; r < 4; r++) {
                float rm = s_acc[mt][0][r];
                #pragma unroll
                for (int nt = 1; nt < 4; nt++) rm = fmaxf(rm, s_acc[mt][nt][r]);
                rm = fmaxf(rm, __shfl_xor(rm, 1, 64));
                rm = fmaxf(rm, __shfl_xor(rm, 2, 64));
                rm = fmaxf(rm, __shfl_xor(rm, 4, 64));
                rm = fmaxf(rm, __shfl_xor(rm, 8, 64));
                float mn = fmaxf(m_st[mt][r], rm);
                float a  = __expf(fmaxf(m_st[mt][r] - mn, -88.0f));
                m_st[mt][r] = mn;
                al[mt][r] = a;
                float rs = 0.f;
                #pragma unroll
                for (int nt = 0; nt < 4; nt++) {
                    float p = __expf(fmaxf(s_acc[mt][nt][r] - mn, -88.0f));
                    s_acc[mt][nt][r] = p;
                    rs += p;
                }
                rs += __shfl_xor(rs, 1, 64);
                rs += __shfl_xor(rs, 2, 64);
                rs += __shfl_xor(rs, 4, 64);
                rs += __shfl_xor(rs, 8, 64);
                l_st[mt][r] = l_st[mt][r] * a + rs;
            }
        #pragma unroll
        for (int mt = 0; mt < 2; mt++)
            #pragma unroll
            for (int nt = 0; nt < 8; nt++)
                #pragma unroll
                for (int r = 0; r < 4; r++)
                    o_acc[mt][nt][r] *= al[mt][r];

        // P -> sP (wave-private rows; stride 64, chunk-of-8 XOR swizzle by row&7)
        #pragma unroll
        for (int mt = 0; mt < 2; mt++)
            #pragma unroll
            for (int nt = 0; nt < 4; nt++)
                #pragma unroll
                for (int r = 0; r < 4; r++) {
                    int prow = wave * 32 + mt * 16 + fq * 4 + r;
                    int col  = nt * 16 + fr;
                    int cw   = (col >> 3) ^ (prow & 7);
                    sP[prow * 64 + (cw << 3) + (col & 7)] = f2bf(s_acc[mt][nt][r]);
                }

        // O += P . V
        #pragma unroll
        for (int kt = 0; kt < 2; kt++) {
            bf16x8 pf[2], vf[8];
            #pragma unroll
            for (int mt = 0; mt < 2; mt++) {
                int prow = wave * 32 + mt * 16 + fr;
                int cw   = (kt * 4 + fq) ^ (prow & 7);
                pf[mt] = *(const bf16x8_a*)(sP + prow * 64 + (cw << 3));
            }
            #pragma unroll
            for (int nt = 0; nt < 8; nt++)
                vf[nt] = *(const bf16x8_a*)(sV + (nt * 16 + fr) * VPAD + kt * 32 + fq * 8);
            #pragma unroll
            for (int mt = 0; mt < 2; mt++)
                #pragma unroll
                for (int nt = 0; nt < 8; nt++)
                    o_acc[mt][nt] = __builtin_amdgcn_mfma_f32_16x16x32_bf16(
                        pf[mt], vf[nt], o_acc[mt][nt], 0, 0, 0);
        }
    }

    // epilogue: O /= l, write ctxT[dh][s]
    #pragma unroll
    for (int mt = 0; mt < 2; mt++) {
        float inv[4];
        #pragma unroll
        for (int r = 0; r < 4; r++) inv[r] = 1.0f / l_st[mt][r];
        const int s0 = qt * 128 + wave * 32 + mt * 16 + fq * 4;
        #pragma unroll
        for (int nt = 0; nt < 8; nt++) {
            ushort4 w;
            w.x = f2b(o_acc[mt][nt][0] * inv[0]);
            w.y = f2b(o_acc[mt][nt][1] * inv[1]);
            w.z = f2b(o_acc[mt][nt][2] * inv[2]);
            w.w = f2b(o_acc[mt][nt][3] * inv[3]);
            int dh = nt * 16 + fr;
            *(ushort4_a*)(Cg + (size_t)dh * SEQ + s0) = w;
        }
    }
}

// =====================================================================
extern "C" void kernel_launch(void* const* d_in, const int* in_sizes, int n_in,
                              void* d_out, int out_size, void* d_ws, size_t ws_size,
                              hipStream_t stream)
{
    const void* x  = d_in[0];
    const void* Wq = d_in[1];
    const void* Wk = d_in[2];
    const void* Wv = d_in[3];
    const void* Wo = d_in[4];
    const void* fc = d_in[5];
    const void* fs = d_in[6];

    const size_t NX = (size_t)NB * SEQ * DIMN;   // 8.39M elems
    const size_t NW = (size_t)DIMN * DIMN;       // 4.19M elems
    unsigned short* wsp = (unsigned short*)d_ws;
    dim3 blk(256);
    const long long SD = (long long)SEQ * DIMN;
    dim3 gcx((int)(NX / 8 / 256));               // convert grid for x-sized bufs
    dim3 gcw((int)(NW / 8 / 256));               // convert grid for W-sized bufs
    dim3 gr((int)(NX / 8 / 256), 2, 1);          // rope
    dim3 gt(SEQ / 32, DIMN / 32, NB);            // transpose
    dim3 gf(SEQ / 128, NB * NH, 1);              // flash
    dim3 gp(DIMN / 128, DIMN / 128, NB);         // out gemm

    const bool fused = ws_size >= (NX + 3 * NW + 3 * NX) * sizeof(unsigned short);

    if (fused) {
        // layout: xb | wqkv(3W) | q,k,v contiguous.  vT<-xb, ctxT<-wqkv, wob<-wqkv+NX
        unsigned short* xb    = wsp;
        unsigned short* wqkv  = xb + NX;
        unsigned short* q_lin = wqkv + 3 * NW;
        unsigned short* k_lin = q_lin + NX;
        unsigned short* v_lin = k_lin + NX;
        unsigned short* vT    = xb;
        unsigned short* ctxT  = wqkv;
        unsigned short* wob   = wqkv + NX;

        convert_kernel<<<gcx, blk, 0, stream>>>(x, xb, (int)(NX / 8), fc);
        convert_kernel<<<gcw, blk, 0, stream>>>(Wq, wqkv,          (int)(NW / 8), fc);
        convert_kernel<<<gcw, blk, 0, stream>>>(Wk, wqkv + NW,     (int)(NW / 8), fc);
        convert_kernel<<<gcw, blk, 0, stream>>>(Wv, wqkv + 2 * NW, (int)(NW / 8), fc);

        dim3 g1(DIMN / 128, (NB * SEQ) / 128, 3);   // fused QKV: z picks W / dest
        gemm_bt<<<g1, blk, 0, stream>>>(xb, wqkv, q_lin, fc, 0,
            DIMN, DIMN, DIMN, DIMN, 3, 0, 0, 0, (long long)NW, 0, (long long)NX, 1.0f);

        rope_kernel<<<gr, blk, 0, stream>>>(q_lin, k_lin, fc, fs);
        transpose_kernel<<<gt, blk, 0, stream>>>(v_lin, vT);
        flash_kernel<<<gf, blk, 0, stream>>>(q_lin, k_lin, vT, ctxT);

        convert_kernel<<<gcw, blk, 0, stream>>>(Wo, wob, (int)(NW / 8), fc);
        gemm_bt<<<gp, blk, 0, stream>>>(ctxT, wob, d_out, fc, 1,
            SEQ, SEQ, DIMN, DIMN, 1, SD, 0, 0, 0, SD, 0, 1.0f);
    } else {
        // layout: xb | wb | q | k | v.  vT<-xb, ctxT<-v_lin, wob<-wb   (75.5 MB)
        unsigned short* xb    = wsp;
        unsigned short* wb    = xb + NX;
        unsigned short* q_lin = wb + NW;
        unsigned short* k_lin = q_lin + NX;
        unsigned short* v_lin = k_lin + NX;
        unsigned short* vT    = xb;
        unsigned short* ctxT  = v_lin;

        convert_kernel<<<gcx, blk, 0, stream>>>(x, xb, (int)(NX / 8), fc);
        dim3 g1(DIMN / 128, (NB * SEQ) / 128, 1);
        convert_kernel<<<gcw, blk, 0, stream>>>(Wq, wb, (int)(NW / 8), fc);
        gemm_bt<<<g1, blk, 0, stream>>>(xb, wb, q_lin, fc, 0,
            DIMN, DIMN, DIMN, DIMN, 1, 0, 0, 0, 0, 0, 0, 1.0f);
        convert_kernel<<<gcw, blk, 0, stream>>>(Wk, wb, (int)(NW / 8), fc);
        gemm_bt<<<g1, blk, 0, stream>>>(xb, wb, k_lin, fc, 0,
            DIMN, DIMN, DIMN, DIMN, 1, 0, 0, 0, 0, 0, 0, 1.0f);
        convert_kernel<<<gcw, blk, 0, stream>>>(Wv, wb, (int)(NW / 8), fc);
        gemm_bt<<<g1, blk, 0, stream>>>(xb, wb, v_lin, fc, 0,
            DIMN, DIMN, DIMN, DIMN, 1, 0, 0, 0, 0, 0, 0, 1.0f);

        rope_kernel<<<gr, blk, 0, stream>>>(q_lin, k_lin, fc, fs);
        transpose_kernel<<<gt, blk, 0, stream>>>(v_lin, vT);
        flash_kernel<<<gf, blk, 0, stream>>>(q_lin, k_lin, vT, ctxT);

        convert_kernel<<<gcw, blk, 0, stream>>>(Wo, wb, (int)(NW / 8), fc);
        gemm_bt<<<gp, blk, 0, stream>>>(ctxT, wb, d_out, fc, 1,
            SEQ, SEQ, DIMN, DIMN, 1, SD, 0, 0, 0, SD, 0, 1.0f);
    }
}

// Round 7
// 477.746 us; speedup vs baseline: 1.7343x; 1.7343x over previous
//
#include <hip/hip_runtime.h>
#include <cstdint>
#include <cstddef>

#define DIMN 2048
#define SEQ  2048
#define NB   2
#define NH   16
#define DH   128
#define NQT  (SEQ / 128)    // 16 q-tiles
#define NBH  (NB * NH)      // 32

typedef __bf16 bf16x8 __attribute__((ext_vector_type(8)));
typedef float  f32x4  __attribute__((ext_vector_type(4)));
typedef bf16x8 __attribute__((may_alias)) bf16x8_a;
typedef ushort4 __attribute__((may_alias)) ushort4_a;
typedef float4 __attribute__((may_alias)) float4_a;

// ---- bf16 <-> f32 helpers on raw ushort storage (RNE, matches np/jnp) ----
__device__ __forceinline__ float b2f(unsigned short b) {
    unsigned u = ((unsigned)b) << 16; float f; __builtin_memcpy(&f, &u, 4); return f;
}
__device__ __forceinline__ unsigned short f2b(float f) {
    unsigned u; __builtin_memcpy(&u, &f, 4);
    u = (u + 0x7FFFu + ((u >> 16) & 1u)) >> 16;
    return (unsigned short)u;
}
__device__ __forceinline__ __bf16 f2bf(float f) {
    unsigned short us = f2b(f); __bf16 h; __builtin_memcpy(&h, &us, 2); return h;
}

// dtype flag: freqs_cos[0]==1.0 -> fp32 word0 = 0x3F800000 (bf16 would be 0x3F803F80)
__device__ __forceinline__ bool dt_is_f32(const void* fc) {
    return ((const unsigned int*)fc)[0] == 0x3F800000u;
}

// async global->LDS, 16B per lane (LDS dest = wave-uniform base + lane*16)
__device__ __forceinline__ void gload_lds16(const unsigned short* g, unsigned short* l) {
    __builtin_amdgcn_global_load_lds(
        (const __attribute__((address_space(1))) void*)g,
        (__attribute__((address_space(3))) void*)l,
        16, 0, 0);
}

// ============== convert fp32 (or bf16 passthrough) -> bf16, 8 elems/thread ==============
__global__ void convert_kernel(const void* __restrict__ in, unsigned short* __restrict__ out,
                               int n8, const void* __restrict__ dt)
{
    const bool isf32 = dt_is_f32(dt);
    int i = blockIdx.x * 256 + threadIdx.x;
    if (i >= n8) return;
    if (isf32) {
        const float* p = (const float*)in + (size_t)i * 8;
        float4 lo = *(const float4_a*)p;
        float4 hi = *(const float4_a*)(p + 4);
        ushort4 a, b;
        a.x = f2b(lo.x); a.y = f2b(lo.y); a.z = f2b(lo.z); a.w = f2b(lo.w);
        b.x = f2b(hi.x); b.y = f2b(hi.y); b.z = f2b(hi.z); b.w = f2b(hi.w);
        *(ushort4_a*)(out + (size_t)i * 8)     = a;
        *(ushort4_a*)(out + (size_t)i * 8 + 4) = b;
    } else {
        const ushort4* p = (const ushort4*)((const char*)in + (size_t)i * 16);
        *(ushort4_a*)(out + (size_t)i * 8)     = p[0];
        *(ushort4_a*)(out + (size_t)i * 8 + 4) = p[1];
    }
}

// =====================================================================
// "bt" GEMM, pure bf16 inputs:  C[m,n] = scale * sum_k A[m,k]*B[n,k]  (fp32 acc)
// cmode: 1 = C dtype follows runtime flag (fp32 if flag), 0 = bf16 always.
// grid.z -> (zb,zh) = (z/Hz, z%Hz).  (m97 structure, global_load_lds width-16)
// =====================================================================
__global__ __launch_bounds__(256, 2) void gemm_bt(
    const unsigned short* __restrict__ A, const unsigned short* __restrict__ B,
    void* __restrict__ C, const void* __restrict__ dt, int cmode,
    int K, int lda, int ldb, int ldc, int Hz,
    long long sAb, long long sAh, long long sBb, long long sBh,
    long long sCb, long long sCh, float scale)
{
    const bool cf32 = cmode && dt_is_f32(dt);

    int bx = blockIdx.x, by = blockIdx.y, z = blockIdx.z;
    int zb = z / Hz, zh = z - zb * Hz;
    const unsigned short* Az = A + zb * sAb + zh * sAh;
    const unsigned short* Bz = B + zb * sBb + zh * sBh;
    const long long coffz = zb * sCb + zh * sCh;
    const int m0 = by * 128, n0 = bx * 128;

    __shared__ alignas(16) unsigned short sA[128 * 32];
    __shared__ alignas(16) unsigned short sB[128 * 32];

    const int tid  = threadIdx.x;
    const int lane = tid & 63, wave = tid >> 6;
    const int waveM = wave >> 1, waveN = wave & 1;

    const int rowA = tid >> 2;          // 0..63
    const int c8   = (tid & 3) << 3;    // 0,8,16,24
    const unsigned short* gA0 = Az + (size_t)(m0 + rowA)      * lda + c8;
    const unsigned short* gA1 = Az + (size_t)(m0 + rowA + 64) * lda + c8;
    const unsigned short* gB0 = Bz + (size_t)(n0 + rowA)      * ldb + c8;
    const unsigned short* gB1 = Bz + (size_t)(n0 + rowA + 64) * ldb + c8;
    unsigned short* lA0 = sA + tid * 8;
    unsigned short* lA1 = sA + 2048 + tid * 8;
    unsigned short* lB0 = sB + tid * 8;
    unsigned short* lB1 = sB + 2048 + tid * 8;

    f32x4 acc[4][4];
    #pragma unroll
    for (int i = 0; i < 4; i++)
        #pragma unroll
        for (int j = 0; j < 4; j++)
            acc[i][j] = (f32x4){0.f, 0.f, 0.f, 0.f};

    const int fr = lane & 15, fq = lane >> 4;
    const int aoff = (waveM * 64 + fr) * 32 + fq * 8;
    const int boff = (waveN * 64 + fr) * 32 + fq * 8;

    for (int kt = 0; kt < K; kt += 32) {
        gload_lds16(gA0, lA0);
        gload_lds16(gA1, lA1);
        gload_lds16(gB0, lB0);
        gload_lds16(gB1, lB1);
        gA0 += 32; gA1 += 32; gB0 += 32; gB1 += 32;
        __syncthreads();

        bf16x8 af[4], bfr[4];
        #pragma unroll
        for (int mt = 0; mt < 4; mt++)
            af[mt] = *(const bf16x8_a*)(sA + aoff + mt * 16 * 32);
        #pragma unroll
        for (int nt = 0; nt < 4; nt++)
            bfr[nt] = *(const bf16x8_a*)(sB + boff + nt * 16 * 32);
        #pragma unroll
        for (int mt = 0; mt < 4; mt++)
            #pragma unroll
            for (int nt = 0; nt < 4; nt++)
                acc[mt][nt] = __builtin_amdgcn_mfma_f32_16x16x32_bf16(
                    af[mt], bfr[nt], acc[mt][nt], 0, 0, 0);
        __syncthreads();
    }

    // C/D layout: col = lane&15 (n), row = (lane>>4)*4 + r (m)
    const int crow0 = m0 + waveM * 64 + fq * 4;
    const int ccol0 = n0 + waveN * 64 + fr;
    #pragma unroll
    for (int mt = 0; mt < 4; mt++)
        #pragma unroll
        for (int nt = 0; nt < 4; nt++) {
            size_t base = (size_t)(crow0 + mt * 16) * ldc + (ccol0 + nt * 16);
            if (cf32) {
                float* Cz = (float*)C + coffz;
                #pragma unroll
                for (int r = 0; r < 4; r++)
                    Cz[base + (size_t)r * ldc] = acc[mt][nt][r] * scale;
            } else {
                unsigned short* Cz = (unsigned short*)C + coffz;
                #pragma unroll
                for (int r = 0; r < 4; r++)
                    Cz[base + (size_t)r * ldc] = f2b(acc[mt][nt][r] * scale);
            }
        }
}

// ============== RoPE in place on q_lin and k_lin [NB*SEQ, DIMN] bf16, 8 elems/thread ==============
__global__ void rope_kernel(unsigned short* q, unsigned short* k,
                            const void* __restrict__ fc,
                            const void* __restrict__ fs)
{
    const bool isf32 = dt_is_f32(fc);
    int idx = blockIdx.x * 256 + threadIdx.x;   // 8-elem group
    unsigned short* p = blockIdx.y ? k : q;
    int row = idx >> 8;                         // [0, NB*SEQ)
    int e   = (idx & 255) << 3;                 // feature 0..2047 step 8
    int s   = row & (SEQ - 1);
    int j0  = (e & (DH - 1)) >> 1;              // 4 pairs j0..j0+3
    float c[4], sn[4];
    #pragma unroll
    for (int t = 0; t < 4; t++) {
        if (isf32) {
            c[t]  = ((const float*)fc)[s * 64 + j0 + t];
            sn[t] = ((const float*)fs)[s * 64 + j0 + t];
        } else {
            c[t]  = b2f(((const unsigned short*)fc)[s * 64 + j0 + t]);
            sn[t] = b2f(((const unsigned short*)fs)[s * 64 + j0 + t]);
        }
    }
    size_t off = (size_t)row * DIMN + e;
    ushort4 a = *(ushort4_a*)(p + off);
    ushort4 b = *(ushort4_a*)(p + off + 4);
    float xs[8] = {b2f(a.x), b2f(a.y), b2f(a.z), b2f(a.w),
                   b2f(b.x), b2f(b.y), b2f(b.z), b2f(b.w)};
    ushort4 oa, ob;
    oa.x = f2b(xs[0] * c[0] - xs[1] * sn[0]);
    oa.y = f2b(xs[0] * sn[0] + xs[1] * c[0]);
    oa.z = f2b(xs[2] * c[1] - xs[3] * sn[1]);
    oa.w = f2b(xs[2] * sn[1] + xs[3] * c[1]);
    ob.x = f2b(xs[4] * c[2] - xs[5] * sn[2]);
    ob.y = f2b(xs[4] * sn[2] + xs[5] * c[2]);
    ob.z = f2b(xs[6] * c[3] - xs[7] * sn[3]);
    ob.w = f2b(xs[6] * sn[3] + xs[7] * c[3]);
    *(ushort4_a*)(p + off)     = oa;
    *(ushort4_a*)(p + off + 4) = ob;
}

// ============== per-batch 2048x2048 transpose: out[i][t] = in[t][i] (bf16) ==============
__global__ void transpose_kernel(const unsigned short* __restrict__ in,
                                 unsigned short* __restrict__ out)
{
    __shared__ unsigned short tile[32][33];
    int b = blockIdx.z;
    const unsigned short* ib = in + (size_t)b * SEQ * DIMN;
    unsigned short*       ob = out + (size_t)b * SEQ * DIMN;
    int t0 = blockIdx.x << 5, i0 = blockIdx.y << 5;
    int c = threadIdx.x & 31, r0 = threadIdx.x >> 5;
    for (int r = r0; r < 32; r += 8)
        tile[r][c] = ib[(size_t)(t0 + r) * DIMN + i0 + c];
    __syncthreads();
    for (int r = r0; r < 32; r += 8)
        ob[(size_t)(i0 + r) * SEQ + t0 + c] = tile[c][r];
}

// =====================================================================
// Fused flash attention (causal). launch_bounds (256,2): R6's (256,3)
// capped VGPRs at 84 -> scratch spills (WRITE_SIZE 16->58MB, 3.2x dur).
// 1D grid, qt DESCENDING (heavy blocks dispatch first -> balanced CUs).
// Block: (q-tile of 128 rows, b, h); wave w owns q rows [w*32, w*32+32).
// KV tiles of 64. Writes ctxT[dh][s] (transposed) directly.
// =====================================================================
#define KPAD 136   // 128 + 8 (16B-mult stride)
#define VPAD 72    // 64 + 8
__global__ __launch_bounds__(256, 2) void flash_kernel(
    const unsigned short* __restrict__ q_lin,
    const unsigned short* __restrict__ k_lin,
    const unsigned short* __restrict__ vTg,
    unsigned short* __restrict__ ctxT)
{
    __shared__ alignas(16) __bf16 sK[64 * KPAD];    // K tile [t][dh]     17408 B
    __shared__ alignas(16) __bf16 sV[DH * VPAD];    // V^T tile [dh][t]   18432 B
    __shared__ alignas(16) __bf16 sP[128 * 64];     // P [q][t] XOR-swz   16384 B

    const int idx = blockIdx.x;                 // [0, NQT*NBH)
    const int qt  = NQT - 1 - (idx >> 5);       // heavy tiles first
    const int z   = idx & (NBH - 1);
    const int b   = z >> 4, h = z & 15;

    const unsigned short* Qg = q_lin + ((size_t)(b * SEQ + qt * 128)) * DIMN + h * DH;
    const unsigned short* Kg = k_lin + (size_t)b * SEQ * DIMN + h * DH;
    const unsigned short* Vg = vTg  + (size_t)b * SEQ * DIMN + (size_t)h * DH * SEQ;
    unsigned short*       Cg = ctxT + (size_t)b * SEQ * DIMN + (size_t)h * DH * SEQ;

    const int tid  = threadIdx.x;
    const int lane = tid & 63, wave = tid >> 6;
    const int fr = lane & 15, fq = lane >> 4;

    // Q fragments (A-layout): row = wave*32 + mt*16 + fr, k = kt*32 + fq*8 + j
    bf16x8 qf[2][4];
    #pragma unroll
    for (int mt = 0; mt < 2; mt++)
        #pragma unroll
        for (int kt = 0; kt < 4; kt++)
            qf[mt][kt] = *(const bf16x8_a*)(Qg + (size_t)(wave * 32 + mt * 16 + fr) * DIMN + kt * 32 + fq * 8);

    f32x4 o_acc[2][8];
    #pragma unroll
    for (int mt = 0; mt < 2; mt++)
        #pragma unroll
        for (int nt = 0; nt < 8; nt++)
            o_acc[mt][nt] = (f32x4){0.f, 0.f, 0.f, 0.f};
    float m_st[2][4], l_st[2][4];
    #pragma unroll
    for (int mt = 0; mt < 2; mt++)
        #pragma unroll
        for (int r = 0; r < 4; r++) { m_st[mt][r] = -1e30f; l_st[mt][r] = 0.f; }

    const float scale = 0.08838834764831845f;
    const int jmax = 2 * qt + 2;

    for (int jt = 0; jt < jmax; jt++) {
        __syncthreads();
        const unsigned short* Kt = Kg + (size_t)jt * 64 * DIMN;
        const unsigned short* Vt = Vg + jt * 64;
        #pragma unroll
        for (int i = 0; i < 4; i++) {
            int cc  = tid + i * 256;
            int row = cc >> 4, col = (cc & 15) << 3;
            *(bf16x8_a*)(sK + row * KPAD + col) = *(const bf16x8_a*)(Kt + (size_t)row * DIMN + col);
        }
        #pragma unroll
        for (int i = 0; i < 4; i++) {
            int cc  = tid + i * 256;
            int row = cc >> 3, col = (cc & 7) << 3;
            *(bf16x8_a*)(sV + row * VPAD + col) = *(const bf16x8_a*)(Vt + (size_t)row * SEQ + col);
        }
        __syncthreads();

        // S = Q . K^T
        f32x4 s_acc[2][4];
        #pragma unroll
        for (int mt = 0; mt < 2; mt++)
            #pragma unroll
            for (int nt = 0; nt < 4; nt++)
                s_acc[mt][nt] = (f32x4){0.f, 0.f, 0.f, 0.f};
        #pragma unroll
        for (int kt = 0; kt < 4; kt++) {
            bf16x8 kf[4];
            #pragma unroll
            for (int nt = 0; nt < 4; nt++)
                kf[nt] = *(const bf16x8_a*)(sK + (nt * 16 + fr) * KPAD + kt * 32 + fq * 8);
            #pragma unroll
            for (int mt = 0; mt < 2; mt++)
                #pragma unroll
                for (int nt = 0; nt < 4; nt++)
                    s_acc[mt][nt] = __builtin_amdgcn_mfma_f32_16x16x32_bf16(
                        qf[mt][kt], kf[nt], s_acc[mt][nt], 0, 0, 0);
        }

        #pragma unroll
        for (int mt = 0; mt < 2; mt++)
            #pragma unroll
            for (int nt = 0; nt < 4; nt++)
                #pragma unroll
                for (int r = 0; r < 4; r++)
                    s_acc[mt][nt][r] *= scale;
        if (jt >= 2 * qt) {
            #pragma unroll
            for (int mt = 0; mt < 2; mt++)
                #pragma unroll
                for (int nt = 0; nt < 4; nt++)
                    #pragma unroll
                    for (int r = 0; r < 4; r++) {
                        int srow = wave * 32 + mt * 16 + fq * 4 + r;
                        int tcol = jt * 64 + nt * 16 + fr - qt * 128;
                        if (tcol > srow) s_acc[mt][nt][r] = -1e30f;
                    }
        }

        // online softmax
        float al[2][4];
        #pragma unroll
        for (int mt = 0; mt < 2; mt++)
            #pragma unroll
            for (int r = 0; r < 4; r++) {
                float rm = s_acc[mt][0][r];
                #pragma unroll
                for (int nt = 1; nt < 4; nt++) rm = fmaxf(rm, s_acc[mt][nt][r]);
                rm = fmaxf(rm, __shfl_xor(rm, 1, 64));
                rm = fmaxf(rm, __shfl_xor(rm, 2, 64));
                rm = fmaxf(rm, __shfl_xor(rm, 4, 64));
                rm = fmaxf(rm, __shfl_xor(rm, 8, 64));
                float mn = fmaxf(m_st[mt][r], rm);
                float a  = __expf(fmaxf(m_st[mt][r] - mn, -88.0f));
                m_st[mt][r] = mn;
                al[mt][r] = a;
                float rs = 0.f;
                #pragma unroll
                for (int nt = 0; nt < 4; nt++) {
                    float p = __expf(fmaxf(s_acc[mt][nt][r] - mn, -88.0f));
                    s_acc[mt][nt][r] = p;
                    rs += p;
                }
                rs += __shfl_xor(rs, 1, 64);
                rs += __shfl_xor(rs, 2, 64);
                rs += __shfl_xor(rs, 4, 64);
                rs += __shfl_xor(rs, 8, 64);
                l_st[mt][r] = l_st[mt][r] * a + rs;
            }
        #pragma unroll
        for (int mt = 0; mt < 2; mt++)
            #pragma unroll
            for (int nt = 0; nt < 8; nt++)
                #pragma unroll
                for (int r = 0; r < 4; r++)
                    o_acc[mt][nt][r] *= al[mt][r];

        // P -> sP (wave-private rows; stride 64, chunk-of-8 XOR swizzle by row&7)
        #pragma unroll
        for (int mt = 0; mt < 2; mt++)
            #pragma unroll
            for (int nt = 0; nt < 4; nt++)
                #pragma unroll
                for (int r = 0; r < 4; r++) {
                    int prow = wave * 32 + mt * 16 + fq * 4 + r;
                    int col  = nt * 16 + fr;
                    int cw   = (col >> 3) ^ (prow & 7);
                    sP[prow * 64 + (cw << 3) + (col & 7)] = f2bf(s_acc[mt][nt][r]);
                }

        // O += P . V
        #pragma unroll
        for (int kt = 0; kt < 2; kt++) {
            bf16x8 pf[2], vf[8];
            #pragma unroll
            for (int mt = 0; mt < 2; mt++) {
                int prow = wave * 32 + mt * 16 + fr;
                int cw   = (kt * 4 + fq) ^ (prow & 7);
                pf[mt] = *(const bf16x8_a*)(sP + prow * 64 + (cw << 3));
            }
            #pragma unroll
            for (int nt = 0; nt < 8; nt++)
                vf[nt] = *(const bf16x8_a*)(sV + (nt * 16 + fr) * VPAD + kt * 32 + fq * 8);
            #pragma unroll
            for (int mt = 0; mt < 2; mt++)
                #pragma unroll
                for (int nt = 0; nt < 8; nt++)
                    o_acc[mt][nt] = __builtin_amdgcn_mfma_f32_16x16x32_bf16(
                        pf[mt], vf[nt], o_acc[mt][nt], 0, 0, 0);
        }
    }

    // epilogue: O /= l, write ctxT[dh][s]
    #pragma unroll
    for (int mt = 0; mt < 2; mt++) {
        float inv[4];
        #pragma unroll
        for (int r = 0; r < 4; r++) inv[r] = 1.0f / l_st[mt][r];
        const int s0 = qt * 128 + wave * 32 + mt * 16 + fq * 4;
        #pragma unroll
        for (int nt = 0; nt < 8; nt++) {
            ushort4 w;
            w.x = f2b(o_acc[mt][nt][0] * inv[0]);
            w.y = f2b(o_acc[mt][nt][1] * inv[1]);
            w.z = f2b(o_acc[mt][nt][2] * inv[2]);
            w.w = f2b(o_acc[mt][nt][3] * inv[3]);
            int dh = nt * 16 + fr;
            *(ushort4_a*)(Cg + (size_t)dh * SEQ + s0) = w;
        }
    }
}

// =====================================================================
extern "C" void kernel_launch(void* const* d_in, const int* in_sizes, int n_in,
                              void* d_out, int out_size, void* d_ws, size_t ws_size,
                              hipStream_t stream)
{
    const void* x  = d_in[0];
    const void* Wq = d_in[1];
    const void* Wk = d_in[2];
    const void* Wv = d_in[3];
    const void* Wo = d_in[4];
    const void* fc = d_in[5];
    const void* fs = d_in[6];

    const size_t NX = (size_t)NB * SEQ * DIMN;   // 8.39M elems
    const size_t NW = (size_t)DIMN * DIMN;       // 4.19M elems
    unsigned short* wsp = (unsigned short*)d_ws;
    dim3 blk(256);
    const long long SD = (long long)SEQ * DIMN;
    dim3 gcx((int)(NX / 8 / 256));               // convert grid for x-sized bufs
    dim3 gcw((int)(NW / 8 / 256));               // convert grid for W-sized bufs
    dim3 gr((int)(NX / 8 / 256), 2, 1);          // rope
    dim3 gt(SEQ / 32, DIMN / 32, NB);            // transpose
    dim3 gf(NQT * NBH, 1, 1);                    // flash (1D, qt descending)
    dim3 gp(DIMN / 128, DIMN / 128, NB);         // out gemm

    const bool fused = ws_size >= (NX + 3 * NW + 3 * NX) * sizeof(unsigned short);

    if (fused) {
        // layout: xb | wqkv(3W) | q,k,v contiguous.  vT<-xb, ctxT<-wqkv, wob<-wqkv+NX
        unsigned short* xb    = wsp;
        unsigned short* wqkv  = xb + NX;
        unsigned short* q_lin = wqkv + 3 * NW;
        unsigned short* k_lin = q_lin + NX;
        unsigned short* v_lin = k_lin + NX;
        unsigned short* vT    = xb;
        unsigned short* ctxT  = wqkv;
        unsigned short* wob   = wqkv + NX;

        convert_kernel<<<gcx, blk, 0, stream>>>(x, xb, (int)(NX / 8), fc);
        convert_kernel<<<gcw, blk, 0, stream>>>(Wq, wqkv,          (int)(NW / 8), fc);
        convert_kernel<<<gcw, blk, 0, stream>>>(Wk, wqkv + NW,     (int)(NW / 8), fc);
        convert_kernel<<<gcw, blk, 0, stream>>>(Wv, wqkv + 2 * NW, (int)(NW / 8), fc);

        dim3 g1(DIMN / 128, (NB * SEQ) / 128, 3);   // fused QKV: z picks W / dest
        gemm_bt<<<g1, blk, 0, stream>>>(xb, wqkv, q_lin, fc, 0,
            DIMN, DIMN, DIMN, DIMN, 3, 0, 0, 0, (long long)NW, 0, (long long)NX, 1.0f);

        rope_kernel<<<gr, blk, 0, stream>>>(q_lin, k_lin, fc, fs);
        transpose_kernel<<<gt, blk, 0, stream>>>(v_lin, vT);
        flash_kernel<<<gf, blk, 0, stream>>>(q_lin, k_lin, vT, ctxT);

        convert_kernel<<<gcw, blk, 0, stream>>>(Wo, wob, (int)(NW / 8), fc);
        gemm_bt<<<gp, blk, 0, stream>>>(ctxT, wob, d_out, fc, 1,
            SEQ, SEQ, DIMN, DIMN, 1, SD, 0, 0, 0, SD, 0, 1.0f);
    } else {
        // layout: xb | wb | q | k | v.  vT<-xb, ctxT<-v_lin, wob<-wb   (75.5 MB)
        unsigned short* xb    = wsp;
        unsigned short* wb    = xb + NX;
        unsigned short* q_lin = wb + NW;
        unsigned short* k_lin = q_lin + NX;
        unsigned short* v_lin = k_lin + NX;
        unsigned short* vT    = xb;
        unsigned short* ctxT  = v_lin;

        convert_kernel<<<gcx, blk, 0, stream>>>(x, xb, (int)(NX / 8), fc);
        dim3 g1(DIMN / 128, (NB * SEQ) / 128, 1);
        convert_kernel<<<gcw, blk, 0, stream>>>(Wq, wb, (int)(NW / 8), fc);
        gemm_bt<<<g1, blk, 0, stream>>>(xb, wb, q_lin, fc, 0,
            DIMN, DIMN, DIMN, DIMN, 1, 0, 0, 0, 0, 0, 0, 1.0f);
        convert_kernel<<<gcw, blk, 0, stream>>>(Wk, wb, (int)(NW / 8), fc);
        gemm_bt<<<g1, blk, 0, stream>>>(xb, wb, k_lin, fc, 0,
            DIMN, DIMN, DIMN, DIMN, 1, 0, 0, 0, 0, 0, 0, 1.0f);
        convert_kernel<<<gcw, blk, 0, stream>>>(Wv, wb, (int)(NW / 8), fc);
        gemm_bt<<<g1, blk, 0, stream>>>(xb, wb, v_lin, fc, 0,
            DIMN, DIMN, DIMN, DIMN, 1, 0, 0, 0, 0, 0, 0, 1.0f);

        rope_kernel<<<gr, blk, 0, stream>>>(q_lin, k_lin, fc, fs);
        transpose_kernel<<<gt, blk, 0, stream>>>(v_lin, vT);
        flash_kernel<<<gf, blk, 0, stream>>>(q_lin, k_lin, vT, ctxT);

        convert_kernel<<<gcw, blk, 0, stream>>>(Wo, wb, (int)(NW / 8), fc);
        gemm_bt<<<gp, blk, 0, stream>>>(ctxT, wb, d_out, fc, 1,
            SEQ, SEQ, DIMN, DIMN, 1, SD, 0, 0, 0, SD, 0, 1.0f);
    }
}